// Round 2
// baseline (423.586 us; speedup 1.0000x reference)
//
#include <hip/hip_runtime.h>
#include <hip/hip_fp16.h>

// Problem constants
#define BB 16
#define NN 1024
#define MAX_ITER 100

constexpr float EPS_F    = 0.1f;
constexpr float INV_EPS  = 10.0f;
constexpr float MU_P     = 0.0009765625f + 1e-8f;      // 1/1024 + 1e-8  (== nu)
constexpr float LOG_MU   = -6.9314615656526045f;       // log(MU_P)
constexpr float THRESH_B = 1.6f;                        // THRESH(0.1) * B(16)

#define SCOPE_AGENT __HIP_MEMORY_SCOPE_AGENT

// Coherent (agent-scope) primitives — validated pattern from round 1.
// Reads: relaxed atomic load (bypasses stale L1). Writes: atomicExch RMW
// (executes at the L2 coherence point). No agent-scope fences in the hot
// loop, so per-XCD L2 is never invalidated.
__device__ __forceinline__ float coh_loadf(float* p) {
    return __hip_atomic_load(p, __ATOMIC_RELAXED, SCOPE_AGENT);
}
__device__ __forceinline__ int coh_loadi(int* p) {
    return __hip_atomic_load(p, __ATOMIC_RELAXED, SCOPE_AGENT);
}
__device__ __forceinline__ void coh_storef(float* p, float v) {
    atomicExch(p, v);
}

// 16-block per-batch barrier, sequence-numbered (target = 16 * seq).
// __syncthreads drains vmcnt before s_barrier, so this block's RMWs are
// durable at the coherence point before the arrival add.
__device__ __forceinline__ void batch_sync(int* cnt, int target) {
    __syncthreads();
    if (threadIdx.x == 0) {
        atomicAdd(cnt, 1);
        while (coh_loadi(cnt) < target) __builtin_amdgcn_s_sleep(1);
    }
    __syncthreads();
}

// ---------------------------------------------------------------------------
// K1: tiny init — zero the contiguous counter region (errB/errTot/errCnt/
// bsync = 7456 dwords) and the 16 cost accumulators in the output.
__global__ __launch_bounds__(1024) void init_kernel(
    int* __restrict__ ctrs, float* __restrict__ outCost)
{
    int gid = blockIdx.x * 1024 + threadIdx.x;
    if (gid < 7456) ctrs[gid] = 0;           // 0x0 == 0.0f for the float parts
    if (gid < BB)   outCost[gid] = 0.f;
}

// ---------------------------------------------------------------------------
// K2: Sinkhorn loop. 256 blocks x 1024 threads (1 block/CU, 16 waves).
// NEW vs round 1:
//  - E (= exp(-C/eps), fp16) lives entirely in REGISTERS: each thread holds
//    its 64 elements (2 uint4 per row x 4 rows = 32 VGPRs), loaded once from
//    C in the prologue. No E buffer, no prep kernel, zero E traffic in-loop.
//  - u is carried in registers (u_prev[4]); v recovered at exit. No u/v/wv
//    global traffic inside the loop.
//  - ONE batch_sync per iteration: every block redundantly reduces all 16
//    Tpart block-partials for all 1024 columns (same ascending order ->
//    bit-identical wv in every block's LDS), so no wv broadcast sync.
//    Tpart is double-buffered by iteration parity: a block cannot re-write
//    parity p before all blocks passed the NEXT sync, which requires all
//    blocks finished reading parity p. Race-free.
__global__ __launch_bounds__(1024, 4) void sink_iter(
    const float* __restrict__ C, float* __restrict__ u, float* __restrict__ v,
    float* __restrict__ Tpart,
    float* __restrict__ errB, float* __restrict__ errTot,
    int* __restrict__ errCnt, int* __restrict__ bsync)
{
    const int tid  = threadIdx.x;
    const int lane = tid & 63;
    const int wav  = tid >> 6;            // 0..15
    const int blk  = blockIdx.x;          // 0..255
    // XCD-grouped mapping (blk%8 ~ XCD): each batch's 16 blocks share one L2.
    const int slot = blk >> 3;            // 0..31
    const int b    = ((blk & 7) << 1) | (slot >> 4);
    const int sub  = slot & 15;

    const float* Cb = C + ((size_t)b << 20);
    float* ub  = u + (b << 10);
    float* vb  = v + (b << 10);
    float* Tb  = Tpart + (b << 15);       // [2][16][1024] per batch
    int*   bs  = bsync + (b << 4);

    __shared__ float part[16][1028];      // wave col-partials (XOR-swizzled)
    __shared__ float wv_lds[1024];        // wv, block-local (XOR-swizzled)
    __shared__ float werr[16];
    __shared__ float errv_s;

    // ---- prologue: this thread's 64 E elements -> fp16 registers ----------
    // Thread covers rows sub*64+wav*4+r (r=0..3), cols [lane*16, lane*16+16).
    uint4 e[4][2];
    #pragma unroll
    for (int r = 0; r < 4; ++r) {
        const float4* C4 = (const float4*)(
            Cb + (((size_t)((sub << 6) + (wav << 2) + r)) << 10) + (lane << 4));
        float4 c0 = C4[0], c1 = C4[1], c2 = C4[2], c3 = C4[3];
        union { uint4 q; __half2 h[4]; } p0, p1;
        p0.h[0] = __floats2half2_rn(__expf(-INV_EPS*c0.x), __expf(-INV_EPS*c0.y));
        p0.h[1] = __floats2half2_rn(__expf(-INV_EPS*c0.z), __expf(-INV_EPS*c0.w));
        p0.h[2] = __floats2half2_rn(__expf(-INV_EPS*c1.x), __expf(-INV_EPS*c1.y));
        p0.h[3] = __floats2half2_rn(__expf(-INV_EPS*c1.z), __expf(-INV_EPS*c1.w));
        p1.h[0] = __floats2half2_rn(__expf(-INV_EPS*c2.x), __expf(-INV_EPS*c2.y));
        p1.h[1] = __floats2half2_rn(__expf(-INV_EPS*c2.z), __expf(-INV_EPS*c2.w));
        p1.h[2] = __floats2half2_rn(__expf(-INV_EPS*c3.x), __expf(-INV_EPS*c3.y));
        p1.h[3] = __floats2half2_rn(__expf(-INV_EPS*c3.z), __expf(-INV_EPS*c3.w));
        e[r][0] = p0.q;
        e[r][1] = p1.q;
    }

    float u_prev[4] = {0.f, 0.f, 0.f, 0.f};
    float t_last = 1.0f;                  // final column total for col==tid
    wv_lds[tid] = 1.0f;                   // wv0 = 1 (all-equal: swizzle moot)
    __syncthreads();

    for (int it = 0; it < MAX_ITER; ++it) {
        const int par = it & 1;

        // ---- wf: wv for cols [lane*16, +16) from swizzled LDS -------------
        float wf[16];
        #pragma unroll
        for (int j = 0; j < 4; ++j) {
            int idx = ((lane << 4) | (j << 2)) ^ ((lane & 7) << 2);
            float4 t4 = *(const float4*)&wv_lds[idx];
            wf[4*j+0] = t4.x; wf[4*j+1] = t4.y; wf[4*j+2] = t4.z; wf[4*j+3] = t4.w;
        }

        // ---- fused pass: u-update + column partials (registers only) ------
        float acc[16];
        #pragma unroll
        for (int k = 0; k < 16; ++k) acc[k] = 0.f;
        float derr = 0.f;
        #pragma unroll
        for (int r = 0; r < 4; ++r) {
            union { uint4 q; __half2 h[4]; } a0, a1;
            a0.q = e[r][0]; a1.q = e[r][1];
            float f[16];
            #pragma unroll
            for (int k = 0; k < 4; ++k) {
                float2 fa = __half22float2(a0.h[k]);
                float2 fb = __half22float2(a1.h[k]);
                f[2*k]   = fa.x; f[2*k+1]   = fa.y;
                f[8+2*k] = fb.x; f[8+2*k+1] = fb.y;
            }
            float s = 0.f;
            #pragma unroll
            for (int k = 0; k < 16; ++k) s = fmaf(f[k], wf[k], s);
            #pragma unroll
            for (int off = 32; off >= 1; off >>= 1) s += __shfl_xor(s, off);
            float un = EPS_F * (LOG_MU - __logf(s));
            derr += fabsf(un - u_prev[r]);
            u_prev[r] = un;
            float wuv = MU_P / s;          // exp(u_new/eps), all lanes have it
            #pragma unroll
            for (int k = 0; k < 16; ++k) acc[k] = fmaf(f[k], wuv, acc[k]);
        }
        if (lane == 0) werr[wav] = derr;

        // wave partials -> LDS (swizzled float4: conflict-free b128)
        #pragma unroll
        for (int j = 0; j < 4; ++j) {
            int idx = ((lane << 4) | (j << 2)) ^ ((lane & 7) << 2);
            *(float4*)&part[wav][idx] =
                make_float4(acc[4*j], acc[4*j+1], acc[4*j+2], acc[4*j+3]);
        }
        __syncthreads();

        // cross-wave reduce (rows ascending) -> block partial -> Tpart
        {
            int pidx = tid ^ (((tid >> 4) & 7) << 2);
            float ts = 0.f;
            #pragma unroll
            for (int w = 0; w < 16; ++w) ts += part[w][pidx];
            coh_storef(&Tb[(par << 14) | (sub << 10) | tid], ts);
        }
        // block err -> per-batch err (RMW)
        if (wav == 0) {
            float ev = (lane < 16) ? werr[lane] : 0.f;
            #pragma unroll
            for (int off = 8; off >= 1; off >>= 1) ev += __shfl_xor(ev, off);
            if (lane == 0) atomicAdd(&errB[(((it << 4) + b) << 2)], ev);
        }

        batch_sync(bs, (it + 1) << 4);     // the ONLY inter-block sync

        // batch err complete -> publish to global (overlaps with phase B)
        if (sub == 0 && tid == 0) {
            float eb = coh_loadf(&errB[(((it << 4) + b) << 2)]);
            atomicAdd(&errTot[it << 2], eb);
            __threadfence();               // order errTot before errCnt
            atomicAdd(&errCnt[it << 2], 1);
        }

        // ---- v-update: every block reduces all 16 partials (col == tid) ---
        {
            float* Tp = Tb + (par << 14);
            float t = 0.f;
            #pragma unroll
            for (int s16 = 0; s16 < 16; ++s16)
                t += coh_loadf(&Tp[(s16 << 10) | tid]);   // ascending: bit-identical
            t_last = t;
            wv_lds[tid ^ (((tid >> 4) & 7) << 2)] = MU_P / t;
        }
        __syncthreads();

        // ---- break check: one-sided wait for all 16 batch publications ----
        if (tid == 0) {
            while (coh_loadi(&errCnt[it << 2]) < 16) __builtin_amdgcn_s_sleep(1);
            errv_s = coh_loadf(&errTot[it << 2]);
        }
        __syncthreads();
        if (errv_s < THRESH_B) break;      // uniform across the grid
    }

    // ---- epilogue writes: final u (this wave's 4 rows) and v (64 cols) ----
    #pragma unroll
    for (int r = 0; r < 4; ++r)
        if (lane == 0) ub[(sub << 6) + (wav << 2) + r] = u_prev[r];
    if ((tid >> 6) == sub)                 // thread holds t_last for col==tid
        vb[tid] = EPS_F * (LOG_MU - __logf(t_last));
}

// ---------------------------------------------------------------------------
// K3: pi = exp((u_i + v_j - C_ij)/eps), copy C, cost via per-block atomicAdd
// (out[0:16] zeroed by init_kernel; order-of-add nondeterminism ~1e-7 rel).
__global__ __launch_bounds__(256) void epilogue(
    const float* __restrict__ C, const float* __restrict__ u, const float* __restrict__ v,
    float* __restrict__ outPi, float* __restrict__ outC, float* __restrict__ outCost)
{
    int blk = blockIdx.x;
    int b = blk >> 10;
    int i = blk & 1023;
    size_t base = (size_t)blk << 10;
    const float4* C4 = (const float4*)(C + base);
    const float4* v4 = (const float4*)(v + ((size_t)b << 10));
    float4* P4 = (float4*)(outPi + base);
    float4* O4 = (float4*)(outC + base);
    float ui = u[(b << 10) + i];
    int t = threadIdx.x;
    float4 c = C4[t];
    float4 vv = v4[t];
    float4 p;
    p.x = __expf((ui + vv.x - c.x) * INV_EPS);
    p.y = __expf((ui + vv.y - c.y) * INV_EPS);
    p.z = __expf((ui + vv.z - c.z) * INV_EPS);
    p.w = __expf((ui + vv.w - c.w) * INV_EPS);
    P4[t] = p;
    O4[t] = c;
    float cp = p.x*c.x + p.y*c.y + p.z*c.z + p.w*c.w;
    #pragma unroll
    for (int off = 32; off >= 1; off >>= 1) cp += __shfl_xor(cp, off);
    __shared__ float ps[4];
    if ((t & 63) == 0) ps[t >> 6] = cp;
    __syncthreads();
    if (t == 0) atomicAdd(&outCost[b], ps[0] + ps[1] + ps[2] + ps[3]);
}

// ---------------------------------------------------------------------------
extern "C" void kernel_launch(void* const* d_in, const int* in_sizes, int n_in,
                              void* d_out, int out_size, void* d_ws, size_t ws_size,
                              hipStream_t stream)
{
    const float* C = (const float*)d_in[2];   // x,y unused (shapes only)
    float* out = (float*)d_out;

    // ws layout (~2.2 MB — E and prep are gone):
    float* u      = (float*)d_ws;             // 16384
    float* v      = u + 16384;                // 16384
    float* Tpart  = v + 16384;                // 2*16*16*1024 = 524288 (2 MB)
    float* errB   = Tpart + 524288;           // 6400  (stride-4 [it][b])
    float* errTot = errB + 6400;              // 400   (stride-4 [it])
    int*   errCnt = (int*)(errTot + 400);     // 400
    int*   bsync  = errCnt + 400;             // 256   (stride-16 [b])
    // errB..bsync are contiguous: 7456 dwords zeroed by init_kernel.

    float* outPi = out + 16;
    float* outC  = out + 16 + (size_t)16777216;

    init_kernel<<<8, 1024, 0, stream>>>((int*)errB, out);

    void* args[] = { (void*)&C, (void*)&u, (void*)&v, (void*)&Tpart,
                     (void*)&errB, (void*)&errTot, (void*)&errCnt, (void*)&bsync };
    hipLaunchCooperativeKernel((void*)sink_iter, dim3(256), dim3(1024),
                               args, 0, stream);

    epilogue<<<16384, 256, 0, stream>>>(C, u, v, outPi, outC, out);
}

// Round 3
// 246.314 us; speedup vs baseline: 1.7197x; 1.7197x over previous
//
#include <hip/hip_runtime.h>
#include <hip/hip_fp16.h>

// Problem constants
#define BB 16
#define NN 1024
#define MAX_ITER 100

constexpr float EPS_F    = 0.1f;
constexpr float INV_EPS  = 10.0f;
constexpr float MU_P     = 0.0009765625f + 1e-8f;      // 1/1024 + 1e-8  (== nu)
constexpr float LOG_MU   = -6.9314615656526045f;       // log(MU_P)
constexpr float THRESH_B = 1.6f;                        // THRESH(0.1) * B(16)

#define SCOPE_AGENT __HIP_MEMORY_SCOPE_AGENT

// Coherent (agent-scope) primitives — validated rounds 0-2.
__device__ __forceinline__ float coh_loadf(float* p) {
    return __hip_atomic_load(p, __ATOMIC_RELAXED, SCOPE_AGENT);
}
__device__ __forceinline__ int coh_loadi(int* p) {
    return __hip_atomic_load(p, __ATOMIC_RELAXED, SCOPE_AGENT);
}
__device__ __forceinline__ void coh_storef(float* p, float v) {
    atomicExch(p, v);
}

// 16-block per-batch barrier, sequence-numbered (target = 16 * seq).
// __syncthreads drains vmcnt before s_barrier, so this block's RMWs are
// durable at the coherence point before the arrival add.
__device__ __forceinline__ void batch_sync(int* cnt, int target) {
    __syncthreads();
    if (threadIdx.x == 0) {
        atomicAdd(cnt, 1);
        while (coh_loadi(cnt) < target) __builtin_amdgcn_s_sleep(1);
    }
    __syncthreads();
}

// ---------------------------------------------------------------------------
// K1: tiny init — zero Tpart (4-deep accumulators) + counters, contiguous:
// Tpart 65536 + errB 6400 + errTot 400 + errCnt 400 + bsync 256 = 72992 dwords.
__global__ __launch_bounds__(1024) void init_kernel(int* __restrict__ zr)
{
    int gid = blockIdx.x * 1024 + threadIdx.x;
    if (gid < 72992) zr[gid] = 0;            // 0x0 == 0.0f for the float parts
}

// ---------------------------------------------------------------------------
// K2: Sinkhorn loop. 256 blocks x 1024 threads (1 block/CU, 16 waves).
// Round-2 wins kept: E=exp(-C/eps) fp16 in REGISTERS (loaded once from C),
// u in registers, ONE batch_sync per iteration.
// Round-2 regression fixed: column totals via atomicAdd into T[it&3][col]
// (16 RMWs/address, 1024 addresses in parallel); after the sync each thread
// does ONE coherent load of the final sum — no redundant 16x re-reads.
// Buffer rotation depth 4: after sync#it each block zeroes its 64-col slice
// of T[(it+2)&3]; first accumulation into it is at iter it+2, reachable only
// after sync#(it+1), by which time every zero is durable (vmcnt drained at
// each block's sync entry). Race-free.
__global__ __launch_bounds__(1024, 4) void sink_iter(
    const float* __restrict__ C, float* __restrict__ u, float* __restrict__ v,
    float* __restrict__ Tpart,
    float* __restrict__ errB, float* __restrict__ errTot,
    int* __restrict__ errCnt, int* __restrict__ bsync)
{
    const int tid  = threadIdx.x;
    const int lane = tid & 63;
    const int wav  = tid >> 6;            // 0..15
    const int blk  = blockIdx.x;          // 0..255
    // XCD-grouped mapping (blk%8 ~ XCD): each batch's 16 blocks share one L2.
    const int slot = blk >> 3;            // 0..31
    const int b    = ((blk & 7) << 1) | (slot >> 4);
    const int sub  = slot & 15;

    const float* Cb = C + ((size_t)b << 20);
    float* ub  = u + (b << 10);
    float* vb  = v + (b << 10);
    float* Tb  = Tpart + (b << 12);       // [4][1024] per batch
    int*   bs  = bsync + (b << 4);

    __shared__ float part[16][1028];      // wave col-partials (XOR-swizzled)
    __shared__ float wv_lds[1024];        // wv, block-local (XOR-swizzled)
    __shared__ float werr[16];
    __shared__ float errv_s;

    // ---- prologue: this thread's 64 E elements -> fp16 registers ----------
    // Thread covers rows sub*64+wav*4+r (r=0..3), cols [lane*16, lane*16+16).
    uint4 e[4][2];
    #pragma unroll
    for (int r = 0; r < 4; ++r) {
        const float4* C4 = (const float4*)(
            Cb + (((size_t)((sub << 6) + (wav << 2) + r)) << 10) + (lane << 4));
        float4 c0 = C4[0], c1 = C4[1], c2 = C4[2], c3 = C4[3];
        union { uint4 q; __half2 h[4]; } p0, p1;
        p0.h[0] = __floats2half2_rn(__expf(-INV_EPS*c0.x), __expf(-INV_EPS*c0.y));
        p0.h[1] = __floats2half2_rn(__expf(-INV_EPS*c0.z), __expf(-INV_EPS*c0.w));
        p0.h[2] = __floats2half2_rn(__expf(-INV_EPS*c1.x), __expf(-INV_EPS*c1.y));
        p0.h[3] = __floats2half2_rn(__expf(-INV_EPS*c1.z), __expf(-INV_EPS*c1.w));
        p1.h[0] = __floats2half2_rn(__expf(-INV_EPS*c2.x), __expf(-INV_EPS*c2.y));
        p1.h[1] = __floats2half2_rn(__expf(-INV_EPS*c2.z), __expf(-INV_EPS*c2.w));
        p1.h[2] = __floats2half2_rn(__expf(-INV_EPS*c3.x), __expf(-INV_EPS*c3.y));
        p1.h[3] = __floats2half2_rn(__expf(-INV_EPS*c3.z), __expf(-INV_EPS*c3.w));
        e[r][0] = p0.q;
        e[r][1] = p1.q;
    }

    float u_prev[4] = {0.f, 0.f, 0.f, 0.f};
    float t_last = 1.0f;                  // final column total for col==tid
    wv_lds[tid] = 1.0f;                   // wv0 = 1
    __syncthreads();

    for (int it = 0; it < MAX_ITER; ++it) {
        const int q = it & 3;

        // ---- wf: wv for cols [lane*16, +16) from swizzled LDS -------------
        float wf[16];
        #pragma unroll
        for (int j = 0; j < 4; ++j) {
            int idx = ((lane << 4) | (j << 2)) ^ ((lane & 7) << 2);
            float4 t4 = *(const float4*)&wv_lds[idx];
            wf[4*j+0] = t4.x; wf[4*j+1] = t4.y; wf[4*j+2] = t4.z; wf[4*j+3] = t4.w;
        }

        // ---- fused pass: u-update + column partials (registers only) ------
        float acc[16];
        #pragma unroll
        for (int k = 0; k < 16; ++k) acc[k] = 0.f;
        float derr = 0.f;
        #pragma unroll
        for (int r = 0; r < 4; ++r) {
            union { uint4 q4; __half2 h[4]; } a0, a1;
            a0.q4 = e[r][0]; a1.q4 = e[r][1];
            float f[16];
            #pragma unroll
            for (int k = 0; k < 4; ++k) {
                float2 fa = __half22float2(a0.h[k]);
                float2 fb = __half22float2(a1.h[k]);
                f[2*k]   = fa.x; f[2*k+1]   = fa.y;
                f[8+2*k] = fb.x; f[8+2*k+1] = fb.y;
            }
            float s = 0.f;
            #pragma unroll
            for (int k = 0; k < 16; ++k) s = fmaf(f[k], wf[k], s);
            #pragma unroll
            for (int off = 32; off >= 1; off >>= 1) s += __shfl_xor(s, off);
            float un = EPS_F * (LOG_MU - __logf(s));
            derr += fabsf(un - u_prev[r]);
            u_prev[r] = un;
            float wuv = MU_P / s;          // exp(u_new/eps), all lanes have it
            #pragma unroll
            for (int k = 0; k < 16; ++k) acc[k] = fmaf(f[k], wuv, acc[k]);
        }
        if (lane == 0) werr[wav] = derr;

        // wave partials -> LDS (swizzled float4: conflict-free b128)
        #pragma unroll
        for (int j = 0; j < 4; ++j) {
            int idx = ((lane << 4) | (j << 2)) ^ ((lane & 7) << 2);
            *(float4*)&part[wav][idx] =
                make_float4(acc[4*j], acc[4*j+1], acc[4*j+2], acc[4*j+3]);
        }
        __syncthreads();

        // cross-wave reduce (rows ascending) -> block partial for col == tid
        // -> accumulate into the shared per-batch column total (16-way RMW)
        {
            int pidx = tid ^ (((tid >> 4) & 7) << 2);
            float ts = 0.f;
            #pragma unroll
            for (int w = 0; w < 16; ++w) ts += part[w][pidx];
            atomicAdd(&Tb[(q << 10) | tid], ts);
        }
        // block err -> per-batch err (RMW)
        if (wav == 0) {
            float ev = (lane < 16) ? werr[lane] : 0.f;
            #pragma unroll
            for (int off = 8; off >= 1; off >>= 1) ev += __shfl_xor(ev, off);
            if (lane == 0) atomicAdd(&errB[(((it << 4) + b) << 2)], ev);
        }

        batch_sync(bs, (it + 1) << 4);     // the ONLY inter-block sync

        // zero our 64-col slice of buffer (it+2)&3 for its reuse at it+2
        if (tid < 64)
            coh_storef(&Tb[(((it + 2) & 3) << 10) | ((sub << 6) + tid)], 0.f);

        // batch err complete -> publish to global (overlaps with v-update)
        if (sub == 0 && tid == 0) {
            float eb = coh_loadf(&errB[(((it << 4) + b) << 2)]);
            atomicAdd(&errTot[it << 2], eb);
            __threadfence();               // order errTot before errCnt
            atomicAdd(&errCnt[it << 2], 1);
        }

        // ---- v-update: ONE coherent load of the final column total -------
        {
            float t = coh_loadf(&Tb[(q << 10) | tid]);
            t_last = t;
            wv_lds[tid ^ (((tid >> 4) & 7) << 2)] = MU_P / t;
        }
        __syncthreads();

        // ---- break check: one-sided wait for all 16 batch publications ----
        if (tid == 0) {
            while (coh_loadi(&errCnt[it << 2]) < 16) __builtin_amdgcn_s_sleep(1);
            errv_s = coh_loadf(&errTot[it << 2]);
        }
        __syncthreads();
        if (errv_s < THRESH_B) break;      // uniform across the grid
    }

    // ---- epilogue writes: final u (this wave's 4 rows) and v (64 cols) ----
    #pragma unroll
    for (int r = 0; r < 4; ++r)
        if (lane == 0) ub[(sub << 6) + (wav << 2) + r] = u_prev[r];
    if ((tid >> 6) == sub)                 // thread holds t_last for col==tid
        vb[tid] = EPS_F * (LOG_MU - __logf(t_last));
}

// ---------------------------------------------------------------------------
// K3: pi = exp((u_i + v_j - C_ij)/eps), copy C, per-block partial cost.
// Cost partial goes to part[blk] (plain store) — NO atomics on out[] (round-2
// lesson: 16384 RMWs on one cache line serialized into 213 us).
__global__ __launch_bounds__(256) void epilogue(
    const float* __restrict__ C, const float* __restrict__ u, const float* __restrict__ v,
    float* __restrict__ outPi, float* __restrict__ outC, float* __restrict__ part)
{
    int blk = blockIdx.x;
    int b = blk >> 10;
    int i = blk & 1023;
    size_t base = (size_t)blk << 10;
    const float4* C4 = (const float4*)(C + base);
    const float4* v4 = (const float4*)(v + ((size_t)b << 10));
    float4* P4 = (float4*)(outPi + base);
    float4* O4 = (float4*)(outC + base);
    float ui = u[(b << 10) + i];
    int t = threadIdx.x;
    float4 c = C4[t];
    float4 vv = v4[t];
    float4 p;
    p.x = __expf((ui + vv.x - c.x) * INV_EPS);
    p.y = __expf((ui + vv.y - c.y) * INV_EPS);
    p.z = __expf((ui + vv.z - c.z) * INV_EPS);
    p.w = __expf((ui + vv.w - c.w) * INV_EPS);
    P4[t] = p;
    O4[t] = c;
    float cp = p.x*c.x + p.y*c.y + p.z*c.z + p.w*c.w;
    #pragma unroll
    for (int off = 32; off >= 1; off >>= 1) cp += __shfl_xor(cp, off);
    __shared__ float ps[4];
    if ((t & 63) == 0) ps[t >> 6] = cp;
    __syncthreads();
    if (t == 0) part[blk] = ps[0] + ps[1] + ps[2] + ps[3];
}

// K4: reduce 1024 partials per batch -> cost[16] (plain store, no atomics).
__global__ __launch_bounds__(1024) void cost_reduce(
    const float* __restrict__ part, float* __restrict__ outCost)
{
    int b = blockIdx.x;
    int t = threadIdx.x;
    float s = part[(b << 10) + t];
    #pragma unroll
    for (int off = 32; off >= 1; off >>= 1) s += __shfl_xor(s, off);
    __shared__ float ps[16];
    if ((t & 63) == 0) ps[t >> 6] = s;
    __syncthreads();
    if (t < 64) {
        float e = (t < 16) ? ps[t] : 0.f;
        #pragma unroll
        for (int off = 8; off >= 1; off >>= 1) e += __shfl_xor(e, off);
        if (t == 0) outCost[b] = e;
    }
}

// ---------------------------------------------------------------------------
extern "C" void kernel_launch(void* const* d_in, const int* in_sizes, int n_in,
                              void* d_out, int out_size, void* d_ws, size_t ws_size,
                              hipStream_t stream)
{
    const float* C = (const float*)d_in[2];   // x,y unused (shapes only)
    float* out = (float*)d_out;

    // ws layout (~0.6 MB):
    float* u      = (float*)d_ws;             // 16384
    float* v      = u + 16384;                // 16384
    float* part   = v + 16384;                // 16384 (epilogue partials)
    float* Tpart  = part + 16384;             // 4*1024*16 = 65536 (4-deep accum)
    float* errB   = Tpart + 65536;            // 6400  (stride-4 [it][b])
    float* errTot = errB + 6400;              // 400   (stride-4 [it])
    int*   errCnt = (int*)(errTot + 400);     // 400
    int*   bsync  = errCnt + 400;             // 256   (stride-16 [b])
    // Tpart..bsync contiguous: 72992 dwords zeroed by init_kernel.

    float* outPi = out + 16;
    float* outC  = out + 16 + (size_t)16777216;

    init_kernel<<<72, 1024, 0, stream>>>((int*)Tpart);

    void* args[] = { (void*)&C, (void*)&u, (void*)&v, (void*)&Tpart,
                     (void*)&errB, (void*)&errTot, (void*)&errCnt, (void*)&bsync };
    hipLaunchCooperativeKernel((void*)sink_iter, dim3(256), dim3(1024),
                               args, 0, stream);

    epilogue<<<16384, 256, 0, stream>>>(C, u, v, outPi, outC, part);
    cost_reduce<<<16, 1024, 0, stream>>>(part, out);
}